// Round 1
// baseline (203.502 us; speedup 1.0000x reference)
//
#include <hip/hip_runtime.h>
#include <math.h>

#define TPB 256
constexpr int Bn = 64;
constexpr int Ln = 262144;          // 2^18
constexpr int S  = 4096;            // chunk/tile size
constexpr int NC = Ln / S;          // 64 chunks per row
constexpr int HA = S + 301;         // halo'd extent (4397)
constexpr int EPT = 18;             // ceil(HA/TPB)
constexpr int HAP = EPT * TPB;      // 4608 padded

constexpr float TWO_PI_F = 6.28318530717958647692f;
constexpr float PI_F = 3.14159265358979323846f;
constexpr float INV_TWO_PI_F = 0.15915494309189533577f;

// wrap count: k = floor((d+pi)/(2pi)), with the reference's dm==-pi & d>0 fixup.
__device__ __forceinline__ int wrap_k(float d) {
    float kf = floorf(__fmaf_rn(d, INV_TWO_PI_F, 0.5f));
    float dm = __fmaf_rn(-kf, TWO_PI_F, d);
    if (dm == -PI_F && d > 0.f) kf -= 1.f;
    return (int)kf;
}

__device__ __forceinline__ int wave_iscan_int(int v) {
    int lane = threadIdx.x & 63;
#pragma unroll
    for (int o = 1; o < 64; o <<= 1) {
        int u = __shfl_up(v, o, 64);
        if (lane >= o) v += u;
    }
    return v;
}

__device__ __forceinline__ int block_escan_int(int v, int* wtot) {
    int tid = threadIdx.x, wid = tid >> 6, lane = tid & 63;
    int inc = wave_iscan_int(v);
    __syncthreads();
    if (lane == 63) wtot[wid] = inc;
    __syncthreads();
    int add = 0;
#pragma unroll
    for (int w = 0; w < TPB / 64; ++w) add += (w < wid) ? wtot[w] : 0;
    return inc - v + add;   // exclusive prefix of per-thread sums
}

__device__ __forceinline__ double block_escan_double(double v, double* wtot) {
    int tid = threadIdx.x, wid = tid >> 6, lane = tid & 63;
    double inc = v;
#pragma unroll
    for (int o = 1; o < 64; o <<= 1) {
        double u = __shfl_up(inc, o, 64);
        if (lane >= o) inc += u;
    }
    __syncthreads();
    if (lane == 63) wtot[wid] = inc;
    __syncthreads();
    double add = 0.0;
#pragma unroll
    for (int w = 0; w < TPB / 64; ++w) add += (w < wid) ? wtot[w] : 0.0;
    return inc - v + add;
}

// K1: per-chunk wrap-count sums
__global__ __launch_bounds__(TPB) void k_chunksum(const float* __restrict__ Ig,
                                                  const float* __restrict__ Qg,
                                                  int* __restrict__ W) {
    __shared__ float sph[S + 1];
    __shared__ int rbuf[TPB / 64];
    const int c = blockIdx.x, b = blockIdx.y;
    const int t0 = c * S;
    const float* Ib = Ig + (size_t)b * Ln;
    const float* Qb = Qg + (size_t)b * Ln;

    for (int li = threadIdx.x; li <= S; li += TPB) {
        int g = t0 - 1 + li;            // g <= t0+S-1 <= Ln-1 always
        float ph = 0.f;
        if (g >= 0) ph = atan2f(Qb[g], Ib[g]);
        sph[li] = ph;
    }
    __syncthreads();
    int sum = 0;
    for (int li = threadIdx.x + 1; li <= S; li += TPB) {
        int g = t0 - 1 + li;            // step index j
        if (g >= 1) sum += wrap_k(sph[li] - sph[li - 1]);
    }
    int lane = threadIdx.x & 63, wid = threadIdx.x >> 6;
#pragma unroll
    for (int o = 32; o > 0; o >>= 1) sum += __shfl_down(sum, o, 64);
    if (lane == 0) rbuf[wid] = sum;
    __syncthreads();
    if (threadIdx.x == 0) {
        int t = 0;
#pragma unroll
        for (int w = 0; w < TPB / 64; ++w) t += rbuf[w];
        W[b * NC + c] = t;
    }
}

// K2: exclusive scan of chunk sums per row (NC==64 lanes)
__global__ void k_scanW(const int* __restrict__ W, int* __restrict__ O) {
    int b = blockIdx.x;
    int v = W[b * NC + threadIdx.x];
    int inc = wave_iscan_int(v);
    O[b * NC + threadIdx.x] = inc - v;
}

// K3: unwrap + moving-average high-pass; writes filt to out, partial sums to PS
__global__ __launch_bounds__(TPB) void k_filt(const float* __restrict__ Ig,
                                              const float* __restrict__ Qg,
                                              const int* __restrict__ O,
                                              float* __restrict__ out,
                                              double* __restrict__ PS) {
    __shared__ float spu[HAP];          // phase -> pu
    __shared__ float ppu[HAP];          // prefix of pu
    __shared__ float smg[HAP];          // magnitude -> prefix of magnitude
    __shared__ int iw[TPB / 64];
    __shared__ double dw[TPB / 64];
    __shared__ double dw2[TPB / 64];
    __shared__ int s150sh;
    __shared__ double rbuf[TPB / 64][4];

    const int c = blockIdx.x, b = blockIdx.y;
    const int t0 = c * S;
    const int base = t0 - 151;
    const int tid = threadIdx.x;
    const float* Ib = Ig + (size_t)b * Ln;
    const float* Qb = Qg + (size_t)b * Ln;

#pragma unroll
    for (int j = 0; j < EPT; ++j) {
        int li = tid + j * TPB;
        int g = base + li;
        float ph = 0.f, m = 0.f;
        if (li < HA && g >= 0 && g < Ln) {
            float iv = Ib[g], qv = Qb[g];
            m = sqrtf(__fmaf_rn(iv, iv, qv * qv));
            ph = atan2f(qv, iv);
        }
        spu[li] = ph;
        smg[li] = m;
    }
    __syncthreads();

    const int seg = tid * EPT;
    int kloc[EPT];
    {
        float prev = (seg > 0) ? spu[seg - 1] : 0.f;   // read before any in-place write
        int run = 0;
#pragma unroll
        for (int i = 0; i < EPT; ++i) {
            int li = seg + i;
            float cur = spu[li];
            int g = base + li;
            int k = 0;
            if (li >= 1 && li < HA && g >= 1 && g < Ln) k = wrap_k(cur - prev);
            run += k;
            kloc[i] = run;                              // thread-local inclusive scan
            prev = cur;
        }
        int excl = block_escan_int(run, iw);
#pragma unroll
        for (int i = 0; i < EPT; ++i)
            if (seg + i == 150) s150sh = excl + kloc[i];  // scan value at li of g=t0-1
        __syncthreads();
        const int oc = O[b * NC + c] - s150sh;
#pragma unroll
        for (int i = 0; i < EPT; ++i) {                 // pu in place (own segment only)
            int li = seg + i;
            int g = base + li;
            float pu = 0.f;
            if (li < HA && g >= 0 && g < Ln)
                pu = spu[li] + (float)(oc + excl + kloc[i]) * TWO_PI_F;
            spu[li] = pu;
        }
    }

    // inclusive prefix sums: pu -> ppu (separate), magnitude in place
    {
        float lpp[EPT], lpm[EPT];
        float rp = 0.f, rm = 0.f;
#pragma unroll
        for (int i = 0; i < EPT; ++i) {
            int li = seg + i;
            rp += spu[li];
            rm += smg[li];
            lpp[i] = rp;
            lpm[i] = rm;
        }
        double ep = block_escan_double((double)rp, dw);
        double em = block_escan_double((double)rm, dw2);
#pragma unroll
        for (int i = 0; i < EPT; ++i) {
            int li = seg + i;
            ppu[li] = (float)(ep + (double)lpp[i]);
            smg[li] = (float)(em + (double)lpm[i]);
        }
    }
    __syncthreads();

    float s1mf = 0.f, s2mf = 0.f, s1pf = 0.f, s2pf = 0.f;
    float* om = out + ((size_t)b * 2) * Ln + t0;
    float* op = out + ((size_t)b * 2 + 1) * Ln + t0;
    constexpr float INV_K = 1.0f / 301.0f;
#pragma unroll
    for (int j = 0; j < S / TPB; ++j) {
        int t = tid + j * TPB;
        int lt = t + 151;
        float xm = smg[lt] - smg[lt - 1];
        float am = (smg[lt + 150] - smg[lt - 151]) * INV_K;
        float fm = xm - am;
        float xp = spu[lt];                             // exact pu value
        float ap = (ppu[lt + 150] - ppu[lt - 151]) * INV_K;
        float fp = xp - ap;
        om[t] = fm;
        op[t] = fp;
        s1mf += fm; s2mf = __fmaf_rn(fm, fm, s2mf);
        s1pf += fp; s2pf = __fmaf_rn(fp, fp, s2pf);
    }
    double a0 = (double)s1mf, a1 = (double)s2mf, a2 = (double)s1pf, a3 = (double)s2pf;
    int lane = tid & 63, wid = tid >> 6;
#pragma unroll
    for (int o = 32; o > 0; o >>= 1) {
        a0 += __shfl_down(a0, o, 64);
        a1 += __shfl_down(a1, o, 64);
        a2 += __shfl_down(a2, o, 64);
        a3 += __shfl_down(a3, o, 64);
    }
    if (lane == 0) { rbuf[wid][0] = a0; rbuf[wid][1] = a1; rbuf[wid][2] = a2; rbuf[wid][3] = a3; }
    __syncthreads();
    if (tid == 0) {
        double t0d = 0, t1d = 0, t2d = 0, t3d = 0;
#pragma unroll
        for (int w = 0; w < TPB / 64; ++w) {
            t0d += rbuf[w][0]; t1d += rbuf[w][1]; t2d += rbuf[w][2]; t3d += rbuf[w][3];
        }
        double* p = PS + (size_t)(b * NC + c) * 4;
        p[0] = t0d; p[1] = t1d; p[2] = t2d; p[3] = t3d;
    }
}

// K3b: per-row stats
__global__ void k_stats(const double* __restrict__ PS, float* __restrict__ ROW) {
    int b = blockIdx.x;
    const double* p = PS + (size_t)(b * NC + threadIdx.x) * 4;
    double a0 = p[0], a1 = p[1], a2 = p[2], a3 = p[3];
#pragma unroll
    for (int o = 32; o > 0; o >>= 1) {
        a0 += __shfl_down(a0, o, 64);
        a1 += __shfl_down(a1, o, 64);
        a2 += __shfl_down(a2, o, 64);
        a3 += __shfl_down(a3, o, 64);
    }
    if (threadIdx.x == 0) {
        double Ld = (double)Ln;
        double mm = a0 / Ld;
        double vm = (a1 - a0 * a0 / Ld) / (Ld - 1.0); vm = vm > 0 ? vm : 0;
        double mp = a2 / Ld;
        double vp = (a3 - a2 * a2 / Ld) / (Ld - 1.0); vp = vp > 0 ? vp : 0;
        float* r = ROW + b * 4;
        r[0] = (float)mm;
        r[1] = (float)(1.0 / (sqrt(vm) + 1e-5));
        r[2] = (float)mp;
        r[3] = (float)(1.0 / (sqrt(vp) + 1e-5));
    }
}

// K4: in-place normalize of d_out
__global__ __launch_bounds__(TPB) void k_norm(float* __restrict__ out,
                                              const float* __restrict__ ROW) {
    const size_t n4 = (size_t)Bn * 2 * Ln / 4;
    size_t stride = (size_t)gridDim.x * blockDim.x;
    for (size_t p4 = (size_t)blockIdx.x * blockDim.x + threadIdx.x; p4 < n4; p4 += stride) {
        size_t p = p4 * 4;
        int b = (int)(p >> 19);             // 2L = 2^19
        int sig = (int)((p >> 18) & 1);     // L = 2^18
        float mean = ROW[b * 4 + sig * 2];
        float scale = ROW[b * 4 + sig * 2 + 1];
        float4 v = reinterpret_cast<float4*>(out)[p4];
        v.x = (v.x - mean) * scale;
        v.y = (v.y - mean) * scale;
        v.z = (v.z - mean) * scale;
        v.w = (v.w - mean) * scale;
        reinterpret_cast<float4*>(out)[p4] = v;
    }
}

extern "C" void kernel_launch(void* const* d_in, const int* in_sizes, int n_in,
                              void* d_out, int out_size, void* d_ws, size_t ws_size,
                              hipStream_t stream) {
    const float* Ig = (const float*)d_in[0];
    const float* Qg = (const float*)d_in[1];
    float* out = (float*)d_out;
    char* ws = (char*)d_ws;
    int* W = (int*)ws;                                      // B*NC ints
    int* O = (int*)(ws + 16384);                            // B*NC ints
    double* PS = (double*)(ws + 32768);                     // B*NC*4 doubles (128 KiB)
    float* ROW = (float*)(ws + 32768 + (size_t)Bn * NC * 4 * sizeof(double));

    dim3 grid(NC, Bn);
    hipLaunchKernelGGL(k_chunksum, grid, dim3(TPB), 0, stream, Ig, Qg, W);
    hipLaunchKernelGGL(k_scanW, dim3(Bn), dim3(64), 0, stream, W, O);
    hipLaunchKernelGGL(k_filt, grid, dim3(TPB), 0, stream, Ig, Qg, O, out, PS);
    hipLaunchKernelGGL(k_stats, dim3(Bn), dim3(64), 0, stream, PS, ROW);
    hipLaunchKernelGGL(k_norm, dim3(2048), dim3(TPB), 0, stream, out, ROW);
}

// Round 2
// 159.282 us; speedup vs baseline: 1.2776x; 1.2776x over previous
//
#include <hip/hip_runtime.h>
#include <math.h>

#define TPB 256
constexpr int Bn = 64;
constexpr int Ln = 262144;          // 2^18
constexpr int S  = 4096;            // chunk/tile size
constexpr int NC = Ln / S;          // 64 chunks per row
constexpr int HA = S + 301;         // halo'd extent (4397)
constexpr int EPT = 18;             // ceil(HA/TPB)
constexpr int HAP = EPT * TPB;      // 4608 padded
constexpr int OPT = S / TPB;        // 16 outputs per thread

constexpr float TWO_PI_F = 6.28318530717958647692f;
constexpr float PI_F = 3.14159265358979323846f;
constexpr float INV_TWO_PI_F = 0.15915494309189533577f;

// wrap count: k = floor((d+pi)/(2pi)), with the reference's dm==-pi & d>0 fixup.
__device__ __forceinline__ int wrap_k(float d) {
    float kf = floorf(__fmaf_rn(d, INV_TWO_PI_F, 0.5f));
    float dm = __fmaf_rn(-kf, TWO_PI_F, d);
    if (dm == -PI_F && d > 0.f) kf -= 1.f;
    return (int)kf;
}

__device__ __forceinline__ int wave_iscan_int(int v) {
    int lane = threadIdx.x & 63;
#pragma unroll
    for (int o = 1; o < 64; o <<= 1) {
        int u = __shfl_up(v, o, 64);
        if (lane >= o) v += u;
    }
    return v;
}

__device__ __forceinline__ int block_escan_int(int v, int* wtot) {
    int tid = threadIdx.x, wid = tid >> 6, lane = tid & 63;
    int inc = wave_iscan_int(v);
    __syncthreads();
    if (lane == 63) wtot[wid] = inc;
    __syncthreads();
    int add = 0;
#pragma unroll
    for (int w = 0; w < TPB / 64; ++w) add += (w < wid) ? wtot[w] : 0;
    return inc - v + add;   // exclusive prefix of per-thread sums
}

__device__ __forceinline__ double block_escan_double(double v, double* wtot) {
    int tid = threadIdx.x, wid = tid >> 6, lane = tid & 63;
    double inc = v;
#pragma unroll
    for (int o = 1; o < 64; o <<= 1) {
        double u = __shfl_up(inc, o, 64);
        if (lane >= o) inc += u;
    }
    __syncthreads();
    if (lane == 63) wtot[wid] = inc;
    __syncthreads();
    double add = 0.0;
#pragma unroll
    for (int w = 0; w < TPB / 64; ++w) add += (w < wid) ? wtot[w] : 0.0;
    return inc - v + add;
}

// K1: per-chunk wrap-count sums
__global__ __launch_bounds__(TPB) void k_chunksum(const float* __restrict__ Ig,
                                                  const float* __restrict__ Qg,
                                                  int* __restrict__ W) {
    __shared__ float sph[S + 1];
    __shared__ int rbuf[TPB / 64];
    const int c = blockIdx.x, b = blockIdx.y;
    const int t0 = c * S;
    const float* Ib = Ig + (size_t)b * Ln;
    const float* Qb = Qg + (size_t)b * Ln;

    for (int li = threadIdx.x; li <= S; li += TPB) {
        int g = t0 - 1 + li;            // g <= t0+S-1 <= Ln-1 always
        float ph = 0.f;
        if (g >= 0) ph = atan2f(Qb[g], Ib[g]);
        sph[li] = ph;
    }
    __syncthreads();
    int sum = 0;
    for (int li = threadIdx.x + 1; li <= S; li += TPB) {
        int g = t0 - 1 + li;            // step index j
        if (g >= 1) sum += wrap_k(sph[li] - sph[li - 1]);
    }
    int lane = threadIdx.x & 63, wid = threadIdx.x >> 6;
#pragma unroll
    for (int o = 32; o > 0; o >>= 1) sum += __shfl_down(sum, o, 64);
    if (lane == 0) rbuf[wid] = sum;
    __syncthreads();
    if (threadIdx.x == 0) {
        int t = 0;
#pragma unroll
        for (int w = 0; w < TPB / 64; ++w) t += rbuf[w];
        W[b * NC + c] = t;
    }
}

// K2: exclusive scan of chunk sums per row (NC==64 lanes)
__global__ void k_scanW(const int* __restrict__ W, int* __restrict__ O) {
    int b = blockIdx.x;
    int v = W[b * NC + threadIdx.x];
    int inc = wave_iscan_int(v);
    O[b * NC + threadIdx.x] = inc - v;
}

// K3: unwrap + moving-average high-pass; writes filt to out, partial sums to PS
// LDS cut to 2 big buffers (37 KB) -> 4 blocks/CU; x-values held in registers.
__global__ __launch_bounds__(TPB, 4) void k_filt(const float* __restrict__ Ig,
                                                 const float* __restrict__ Qg,
                                                 const int* __restrict__ O,
                                                 float* __restrict__ out,
                                                 double* __restrict__ PS) {
    __shared__ float spu[HAP];          // phase -> pu -> prefix(pu)
    __shared__ float smg[HAP];          // magnitude -> prefix(magnitude)
    __shared__ int iw[TPB / 64];
    __shared__ double dw[TPB / 64];
    __shared__ int s150sh;
    __shared__ double rbuf[TPB / 64][4];

    const int c = blockIdx.x, b = blockIdx.y;
    const int t0 = c * S;
    const int base = t0 - 151;
    const int tid = threadIdx.x;
    const float* Ib = Ig + (size_t)b * Ln;
    const float* Qb = Qg + (size_t)b * Ln;

#pragma unroll
    for (int j = 0; j < EPT; ++j) {
        int li = tid + j * TPB;
        int g = base + li;
        float ph = 0.f, m = 0.f;
        if (li < HA && g >= 0 && g < Ln) {
            float iv = Ib[g], qv = Qb[g];
            m = sqrtf(__fmaf_rn(iv, iv, qv * qv));
            ph = atan2f(qv, iv);
        }
        spu[li] = ph;
        smg[li] = m;
    }
    __syncthreads();

    const int seg = tid * EPT;
    const float prev0 = (seg > 0) ? spu[seg - 1] : 0.f;

    // pass 1: per-thread wrap-count sum (+ capture scan value at li==150)
    int run = 0, my150 = 0;
    {
        float prev = prev0;
#pragma unroll
        for (int i = 0; i < EPT; ++i) {
            int li = seg + i;
            float cur = spu[li];
            int g = base + li;
            int k = 0;
            if (li >= 1 && li < HA && g >= 1 && g < Ln) k = wrap_k(cur - prev);
            run += k;
            if (li == 150) my150 = run;
            prev = cur;
        }
    }
    int excl = block_escan_int(run, iw);
    if (150 >= seg && 150 < seg + EPT) s150sh = excl + my150;
    __syncthreads();
    const int oc = O[b * NC + c] - s150sh;

    // pass 2: recompute wrap counts, write pu in place (own segment only)
    {
        float prev = prev0;
        int r2 = 0;
#pragma unroll
        for (int i = 0; i < EPT; ++i) {
            int li = seg + i;
            int g = base + li;
            float cur = spu[li];
            int k = 0;
            if (li >= 1 && li < HA && g >= 1 && g < Ln) k = wrap_k(cur - prev);
            r2 += k;
            float pu = 0.f;
            if (li < HA && g >= 0 && g < Ln)
                pu = cur + (float)(oc + excl + r2) * TWO_PI_F;
            spu[li] = pu;
            prev = cur;
        }
    }
    __syncthreads();

    // gather this thread's output x-values into registers BEFORE prefix overwrite
    float xp[OPT], xm[OPT];
#pragma unroll
    for (int j = 0; j < OPT; ++j) {
        int lt = tid + j * TPB + 151;
        xp[j] = spu[lt];
        xm[j] = smg[lt];
    }

    // own-segment sums for block scan
    float rp = 0.f, rm = 0.f;
#pragma unroll
    for (int i = 0; i < EPT; ++i) {
        rp += spu[seg + i];
        rm += smg[seg + i];
    }
    double ep = block_escan_double((double)rp, dw);   // barrier inside protects gathers
    double em = block_escan_double((double)rm, dw);

    // in-place inclusive prefix (own segment only)
    {
        double runp = ep, runm = em;
#pragma unroll
        for (int i = 0; i < EPT; ++i) {
            int li = seg + i;
            runp += (double)spu[li];
            spu[li] = (float)runp;
            runm += (double)smg[li];
            smg[li] = (float)runm;
        }
    }
    __syncthreads();

    float s1mf = 0.f, s2mf = 0.f, s1pf = 0.f, s2pf = 0.f;
    float* om = out + ((size_t)b * 2) * Ln + t0;
    float* op = out + ((size_t)b * 2 + 1) * Ln + t0;
    constexpr float INV_K = 1.0f / 301.0f;
#pragma unroll
    for (int j = 0; j < OPT; ++j) {
        int t = tid + j * TPB;
        int lt = t + 151;
        float am = (smg[lt + 150] - smg[lt - 151]) * INV_K;
        float fm = xm[j] - am;
        float ap = (spu[lt + 150] - spu[lt - 151]) * INV_K;
        float fp = xp[j] - ap;
        om[t] = fm;
        op[t] = fp;
        s1mf += fm; s2mf = __fmaf_rn(fm, fm, s2mf);
        s1pf += fp; s2pf = __fmaf_rn(fp, fp, s2pf);
    }
    double a0 = (double)s1mf, a1 = (double)s2mf, a2 = (double)s1pf, a3 = (double)s2pf;
    int lane = tid & 63, wid = tid >> 6;
#pragma unroll
    for (int o = 32; o > 0; o >>= 1) {
        a0 += __shfl_down(a0, o, 64);
        a1 += __shfl_down(a1, o, 64);
        a2 += __shfl_down(a2, o, 64);
        a3 += __shfl_down(a3, o, 64);
    }
    if (lane == 0) { rbuf[wid][0] = a0; rbuf[wid][1] = a1; rbuf[wid][2] = a2; rbuf[wid][3] = a3; }
    __syncthreads();
    if (tid == 0) {
        double t0d = 0, t1d = 0, t2d = 0, t3d = 0;
#pragma unroll
        for (int w = 0; w < TPB / 64; ++w) {
            t0d += rbuf[w][0]; t1d += rbuf[w][1]; t2d += rbuf[w][2]; t3d += rbuf[w][3];
        }
        double* p = PS + (size_t)(b * NC + c) * 4;
        p[0] = t0d; p[1] = t1d; p[2] = t2d; p[3] = t3d;
    }
}

// K3b: per-row stats
__global__ void k_stats(const double* __restrict__ PS, float* __restrict__ ROW) {
    int b = blockIdx.x;
    const double* p = PS + (size_t)(b * NC + threadIdx.x) * 4;
    double a0 = p[0], a1 = p[1], a2 = p[2], a3 = p[3];
#pragma unroll
    for (int o = 32; o > 0; o >>= 1) {
        a0 += __shfl_down(a0, o, 64);
        a1 += __shfl_down(a1, o, 64);
        a2 += __shfl_down(a2, o, 64);
        a3 += __shfl_down(a3, o, 64);
    }
    if (threadIdx.x == 0) {
        double Ld = (double)Ln;
        double mm = a0 / Ld;
        double vm = (a1 - a0 * a0 / Ld) / (Ld - 1.0); vm = vm > 0 ? vm : 0;
        double mp = a2 / Ld;
        double vp = (a3 - a2 * a2 / Ld) / (Ld - 1.0); vp = vp > 0 ? vp : 0;
        float* r = ROW + b * 4;
        r[0] = (float)mm;
        r[1] = (float)(1.0 / (sqrt(vm) + 1e-5));
        r[2] = (float)mp;
        r[3] = (float)(1.0 / (sqrt(vp) + 1e-5));
    }
}

// K4: in-place normalize of d_out
__global__ __launch_bounds__(TPB) void k_norm(float* __restrict__ out,
                                              const float* __restrict__ ROW) {
    const size_t n4 = (size_t)Bn * 2 * Ln / 4;
    size_t stride = (size_t)gridDim.x * blockDim.x;
    for (size_t p4 = (size_t)blockIdx.x * blockDim.x + threadIdx.x; p4 < n4; p4 += stride) {
        size_t p = p4 * 4;
        int b = (int)(p >> 19);             // 2L = 2^19
        int sig = (int)((p >> 18) & 1);     // L = 2^18
        float mean = ROW[b * 4 + sig * 2];
        float scale = ROW[b * 4 + sig * 2 + 1];
        float4 v = reinterpret_cast<float4*>(out)[p4];
        v.x = (v.x - mean) * scale;
        v.y = (v.y - mean) * scale;
        v.z = (v.z - mean) * scale;
        v.w = (v.w - mean) * scale;
        reinterpret_cast<float4*>(out)[p4] = v;
    }
}

extern "C" void kernel_launch(void* const* d_in, const int* in_sizes, int n_in,
                              void* d_out, int out_size, void* d_ws, size_t ws_size,
                              hipStream_t stream) {
    const float* Ig = (const float*)d_in[0];
    const float* Qg = (const float*)d_in[1];
    float* out = (float*)d_out;
    char* ws = (char*)d_ws;
    int* W = (int*)ws;                                      // B*NC ints
    int* O = (int*)(ws + 16384);                            // B*NC ints
    double* PS = (double*)(ws + 32768);                     // B*NC*4 doubles (128 KiB)
    float* ROW = (float*)(ws + 32768 + (size_t)Bn * NC * 4 * sizeof(double));

    dim3 grid(NC, Bn);
    hipLaunchKernelGGL(k_chunksum, grid, dim3(TPB), 0, stream, Ig, Qg, W);
    hipLaunchKernelGGL(k_scanW, dim3(Bn), dim3(64), 0, stream, W, O);
    hipLaunchKernelGGL(k_filt, grid, dim3(TPB), 0, stream, Ig, Qg, O, out, PS);
    hipLaunchKernelGGL(k_stats, dim3(Bn), dim3(64), 0, stream, PS, ROW);
    hipLaunchKernelGGL(k_norm, dim3(2048), dim3(TPB), 0, stream, out, ROW);
}